// Round 12
// baseline (337.895 us; speedup 1.0000x reference)
//
#include <hip/hip_runtime.h>
#include <hip/hip_bf16.h>
#include <string.h>

#define BB 1024
#define TT 256
#define DD 128
#define KK 4
#define CC 500
#define NEGF (-4294967296.0f)   // float(-2**32+1) rounds to -2^32
#define EPSL 1e-3f

typedef __attribute__((ext_vector_type(8))) short bf16x8;
typedef __attribute__((ext_vector_type(4))) float f32x4;

// ---------- helpers ----------

__device__ __forceinline__ float fast_tanh(float x){
  float ax = fabsf(x);
  float e  = __expf(2.0f * ax);
  float t  = 1.0f - 2.0f * __builtin_amdgcn_rcpf(e + 1.0f);  // e=inf -> rcp=0 -> t=1
  return copysignf(t, x);
}

__device__ __forceinline__ unsigned short bfbits(float f){
  __hip_bfloat16 h = __float2bfloat16(f);
  unsigned short u;
  memcpy(&u, &h, 2);
  return u;
}
__device__ __forceinline__ float bf2f(unsigned short u){
  return __uint_as_float(((unsigned)u) << 16);
}

__device__ __forceinline__ float wave_sum(float v){
  #pragma unroll
  for (int o = 32; o > 0; o >>= 1) v += __shfl_xor(v, o);
  return v;
}
__device__ __forceinline__ float wave_max(float v){
  #pragma unroll
  for (int o = 32; o > 0; o >>= 1) v = fmaxf(v, __shfl_xor(v, o));
  return v;
}

// ---------- K0: pack weights (B-pattern frags, hi/lo) + W3T/CT  [round-5 verbatim] ----------
// frag = (w*4 + kt)*8 + n ; lane l holds W[k0+j][col], col = n*16+(l&15),
// k0 = kt*32+(l>>4)*8.  Used in the MFMA A-slot this reads as W^T (A[r][k]=W[k][n*16+r]).

__global__ __launch_bounds__(256) void k_preppack(
    const float* __restrict__ W1, const float* __restrict__ W3,
    const float* __restrict__ Wk1, const float* __restrict__ Cmat,
    uint4* __restrict__ whi, uint4* __restrict__ wlo,
    float* __restrict__ W3T, float* __restrict__ CT)
{
  int gid = blockIdx.x * 256 + threadIdx.x;
  if (gid < 12288){
    int lane = gid & 63;
    int frag = gid >> 6;
    int n = frag & 7, kt = (frag >> 3) & 3, w = frag >> 5;
    const float* Wp = (w == 0) ? W1 : (w == 1) ? W3 : (Wk1 + (long)(w - 2) * DD * DD);
    int col = n * 16 + (lane & 15);
    int k0 = kt * 32 + (lane >> 4) * 8;
    unsigned int H[4], L[4];
    #pragma unroll
    for (int d = 0; d < 4; ++d){
      float v0 = Wp[(long)(k0 + 2 * d) * DD + col];
      float v1 = Wp[(long)(k0 + 2 * d + 1) * DD + col];
      unsigned short h0 = bfbits(v0); unsigned short l0 = bfbits(v0 - bf2f(h0));
      unsigned short h1 = bfbits(v1); unsigned short l1 = bfbits(v1 - bf2f(h1));
      H[d] = (unsigned)h0 | ((unsigned)h1 << 16);
      L[d] = (unsigned)l0 | ((unsigned)l1 << 16);
    }
    whi[gid] = make_uint4(H[0], H[1], H[2], H[3]);
    wlo[gid] = make_uint4(L[0], L[1], L[2], L[3]);
  } else {
    int j = gid - 12288;
    if (j < DD * DD){
      int a = j >> 7, e = j & 127;
      W3T[j] = W3[e * DD + a];
    } else {
      j -= DD * DD;
      if (j < DD * CC){
        int e = j / CC, c = j - e * CC;
        CT[j] = Cmat[c * DD + e];
      }
    }
  }
}

// ---------- K1: fused 6x GEMM, SWAPPED operands (y^T = W^T · x^T), 16x16x32 ----------
// All fragment layouts are the ones verified by rounds 2-10's passing kernels:
// W frags (k_preppack, unchanged) in the A-slot -> A = W^T;
// x staged exactly as round 5 (rows of 256B, XOR-swizzled) read into the B-slot -> B = x^T.
// C/D (verified): col=lane&15 = token, row=(lane>>4)*4+j = feat.
// => tanh-dot over 128 feats is IN-LANE (32 fma) + 2 shfls; W frags identical
// across all 8 waves (L1 broadcast). Wave wv owns token tile tt=wv (16 tokens).

__global__ __launch_bounds__(512, 4) void k_big6m(
    const float* __restrict__ item, const float* __restrict__ pos,
    const uint4* __restrict__ whi, const uint4* __restrict__ wlo,
    const float* __restrict__ W2, const float* __restrict__ Wk2,
    float* __restrict__ att, float* __restrict__ h2log, float* __restrict__ lnstats)
{
  __shared__ uint4 smem4[4096];                 // 64 KiB: x hi [128]x256B, lo at +32KB
  __shared__ float vsh[5][DD];                  // 2.5 KB dot vectors (W2, Wk2[0..3])
  __shared__ float dscr[5][128];                // 2.5 KB per-pass dot results
  __shared__ float sscr[2][128];                // 1 KB  W3 LN-stat results (s, q)
  char* smem = (char*)smem4;
  const int tid = threadIdx.x, lane = tid & 63, wv = tid >> 6;
  const int tt = wv;                            // token tile (16 tokens) per wave
  const long rbase = (long)blockIdx.x * 128;
  const int r15 = lane & 15, g = lane >> 4;
  const f32x4 ZV = {0.f, 0.f, 0.f, 0.f};

  // ---- stage x = item+pos as hi/lo bf16, rows of 256B, XOR-swizzled [round-5 verbatim] ----
  #pragma unroll
  for (int it = 0; it < 4; ++it){
    int cid = tid + it * 512;                   // 2048 chunks of 8 elems
    int row = cid >> 4, c0 = (cid & 15) * 8;
    const float* src = item + (rbase + row) * DD + c0;
    const float* ps  = pos + (int)((rbase + row) & 255) * DD + c0;
    float4 f0 = *(const float4*)src;
    float4 f1 = *(const float4*)(src + 4);
    float4 p0 = *(const float4*)ps;
    float4 p1 = *(const float4*)(ps + 4);
    float v[8] = {f0.x + p0.x, f0.y + p0.y, f0.z + p0.z, f0.w + p0.w,
                  f1.x + p1.x, f1.y + p1.y, f1.z + p1.z, f1.w + p1.w};
    unsigned int H[4], L[4];
    #pragma unroll
    for (int d = 0; d < 4; ++d){
      unsigned short h0 = bfbits(v[2 * d]);     unsigned short l0 = bfbits(v[2 * d]     - bf2f(h0));
      unsigned short h1 = bfbits(v[2 * d + 1]); unsigned short l1 = bfbits(v[2 * d + 1] - bf2f(h1));
      H[d] = (unsigned)h0 | ((unsigned)h1 << 16);
      L[d] = (unsigned)l0 | ((unsigned)l1 << 16);
    }
    int byt = (c0 * 2) ^ ((row & 7) << 4);
    *(uint4*)(smem + row * 256 + byt)         = make_uint4(H[0], H[1], H[2], H[3]);
    *(uint4*)(smem + 32768 + row * 256 + byt) = make_uint4(L[0], L[1], L[2], L[3]);
  }
  for (int i = tid; i < 5 * DD; i += 512){
    int w = i >> 7, f = i & 127;
    vsh[w][f] = (w == 0) ? W2[f] : Wk2[(w - 1) * DD + f];
  }
  __syncthreads();

  const int WL6[6] = {0, 2, 3, 4, 5, 1};        // W3 (stats) last; vsh[wi] for wi<5

  #pragma unroll
  for (int wi = 0; wi < 6; ++wi){
    const int w = WL6[wi];
    f32x4 acc[8];
    #pragma unroll
    for (int nf = 0; nf < 8; ++nf) acc[nf] = ZV;

    __builtin_amdgcn_s_setprio(1);
    #pragma unroll
    for (int kt = 0; kt < 4; ++kt){
      // x fragment for this wave's token tile (B-slot -> x^T)
      int row = tt * 16 + r15;
      int byt = (kt * 64 + g * 16) ^ ((row & 7) << 4);
      bf16x8 bh = *(const bf16x8*)(smem + row * 256 + byt);
      bf16x8 bl = *(const bf16x8*)(smem + 32768 + row * 256 + byt);
      // W fragments (A-slot -> W^T); identical addresses across waves -> L1 broadcast
      const uint4* ahp = whi + (long)((w * 4 + kt) * 8) * 64 + lane;
      const uint4* alp = wlo + (long)((w * 4 + kt) * 8) * 64 + lane;
      #pragma unroll
      for (int nf = 0; nf < 8; ++nf){
        uint4 ahu = ahp[nf * 64], alu = alp[nf * 64];
        bf16x8 ah = *(const bf16x8*)&ahu;
        bf16x8 al = *(const bf16x8*)&alu;
        acc[nf] = __builtin_amdgcn_mfma_f32_16x16x32_bf16(ah, bh, acc[nf], 0, 0, 0);
        acc[nf] = __builtin_amdgcn_mfma_f32_16x16x32_bf16(ah, bl, acc[nf], 0, 0, 0);
        acc[nf] = __builtin_amdgcn_mfma_f32_16x16x32_bf16(al, bh, acc[nf], 0, 0, 0);
      }
    }
    __builtin_amdgcn_s_setprio(0);

    // lane holds y^T[feat = nf*16 + g*4 + j][token = tt*16 + r15]
    if (w != 1){
      float pd = 0.f;
      #pragma unroll
      for (int nf = 0; nf < 8; ++nf)
        #pragma unroll
        for (int j = 0; j < 4; ++j)
          pd = fmaf(fast_tanh(acc[nf][j]), vsh[wi][nf * 16 + g * 4 + j], pd);
      pd += __shfl_xor(pd, 16);
      pd += __shfl_xor(pd, 32);
      if (lane < 16) dscr[wi][tt * 16 + lane] = pd;
    } else {
      float s = 0.f, q = 0.f;
      #pragma unroll
      for (int nf = 0; nf < 8; ++nf)
        #pragma unroll
        for (int j = 0; j < 4; ++j){
          float y = acc[nf][j];
          s += y; q = fmaf(y, y, q);
        }
      s += __shfl_xor(s, 16); s += __shfl_xor(s, 32);
      q += __shfl_xor(q, 16); q += __shfl_xor(q, 32);
      if (lane < 16){
        sscr[0][tt * 16 + lane] = s;
        sscr[1][tt * 16 + lane] = q;
      }
    }
  }
  __syncthreads();

  // ---- single combined epilogue: write att/h2log/lnstats ----
  if (tid < 128){
    long rg = rbase + tid;
    long b = rg >> 8; int t = (int)(rg & 255);
    att[rg] = dscr[0][tid];
    #pragma unroll
    for (int wi = 1; wi < 5; ++wi)
      h2log[(b * KK + (wi - 1)) * TT + t] = dscr[wi][tid];
    float s = sscr[0][tid];
    float q = sscr[1][tid];
    float mu = s * (1.f / DD);
    float var = q * (1.f / DD) - mu * mu;
    float rs = rsqrtf(var + EPSL);
    float2 st; st.x = mu; st.y = rs;
    *(float2*)&lnstats[rg * 2] = st;
  }
}

// ---------- K2: fused per-batch pipeline, occupancy-first (~39 KB LDS) ----------

__global__ __launch_bounds__(256, 4) void k_fused(
    const float* __restrict__ item, const float* __restrict__ pos,
    const int* __restrict__ mask, const float* __restrict__ att,
    const float* __restrict__ h2log, const float* __restrict__ lnstats,
    const float* __restrict__ Cmat, const float* __restrict__ CT,
    const float* __restrict__ W3, const float* __restrict__ W3T,
    const float* __restrict__ g1, const float* __restrict__ b1,
    const float* __restrict__ g2, const float* __restrict__ b2,
    const float* __restrict__ g3, const float* __restrict__ b3,
    const float* __restrict__ g4, const float* __restrict__ b4,
    const float* __restrict__ W4, float* __restrict__ out)
{
  __shared__ float arena[4096];         // 16 KB phase-shared
  __shared__ float pkt_s[KK][TT];       // 4 KB
  __shared__ float P_s[KK][TT];         // 4 KB
  __shared__ float lnc_s[KK][DD];       // 2 KB
  __shared__ float cu_s[KK][DD];        // 2 KB
  __shared__ float vk_s[KK][DD];        // 2 KB
  __shared__ float cw3s[KK][DD];        // 2 KB (gl-temp, cW3 later)
  __shared__ float ies_s[KK][DD];       // 2 KB
  __shared__ float a_s[TT];             // 1 KB
  __shared__ int   m0s[TT];             // 1 KB
  __shared__ float g1s[DD], b1s[DD];    // 1 KB
  __shared__ float cas[DD], w4s[DD];    // 1 KB
  __shared__ float rbuf[32];
  __shared__ float sel_v[KK];
  __shared__ int   sel_i[KK];
  __shared__ float SkTk[2][KK];

  const int tid = threadIdx.x;
  const long b = blockIdx.x;
  const int lane = tid & 63, wv = tid >> 6;

  float attv = att[b * TT + tid];
  int   mk   = mask[b * TT + tid];
  if (tid < DD){ g1s[tid] = g1[tid]; b1s[tid] = b1[tid]; }
  m0s[tid] = (mk == 0);

  // ---- att softmax -> a_s ----
  {
    float v = (mk == 0) ? NEGF : attv;
    float wm = wave_max(v);
    if (lane == 0) rbuf[wv] = wm;
    __syncthreads();
    float mx = fmaxf(fmaxf(rbuf[0], rbuf[1]), fmaxf(rbuf[2], rbuf[3]));
    float ex = __expf(v - mx);
    float ws = wave_sum(ex);
    if (lane == 0) rbuf[4 + wv] = ws;
    __syncthreads();
    float sm = rbuf[4] + rbuf[5] + rbuf[6] + rbuf[7];
    a_s[tid] = ex / sm;
  }
  __syncthreads();

  const float4* item4 = (const float4*)(item + (long)b * TT * DD);
  const float4* pos4  = (const float4*)pos;

  // ---- z_u = x^T a ----
  {
    int q = tid & 31, h = tid >> 5;
    float4 acc = {0.f, 0.f, 0.f, 0.f};
    for (int t = h; t < TT; t += 8){
      float4 xi = item4[t * 32 + q];
      float4 pp = pos4[t * 32 + q];
      float av = a_s[t];
      acc.x = fmaf(av, xi.x + pp.x, acc.x);
      acc.y = fmaf(av, xi.y + pp.y, acc.y);
      acc.z = fmaf(av, xi.z + pp.z, acc.z);
      acc.w = fmaf(av, xi.w + pp.w, acc.w);
    }
    *(float4*)&arena[h * 128 + q * 4] = acc;      // zpart[8][128]
    __syncthreads();
    if (tid < DD){
      float z = 0.f;
      #pragma unroll
      for (int h2 = 0; h2 < 8; ++h2) z += arena[h2 * 128 + tid];
      arena[1024 + tid] = z;                      // zs
    }
    __syncthreads();
  }
  float* zs  = arena + 1024;                      // [128]
  float* s_s = arena + 1152;                      // [512]

  // ---- s_u = z_u @ C^T ----
  for (int c = tid; c < 512; c += 256){
    float s = -3.0e38f;
    if (c < CC){
      s = 0.f;
      for (int e = 0; e < DD; ++e) s = fmaf(zs[e], CT[e * CC + c], s);
    }
    s_s[c] = s;
  }
  __syncthreads();

  // ---- top-4 (descending, ties -> lowest index) ----
  for (int k = 0; k < KK; ++k){
    float bv = -3.0e38f; int bi = 1 << 20;
    for (int c = tid; c < 512; c += 256){
      float sv = s_s[c];
      if (sv > bv || (sv == bv && c < bi)){ bv = sv; bi = c; }
    }
    #pragma unroll
    for (int o = 32; o > 0; o >>= 1){
      float ov = __shfl_xor(bv, o); int oi = __shfl_xor(bi, o);
      if (ov > bv || (ov == bv && oi < bi)){ bv = ov; bi = oi; }
    }
    if (lane == 0){ rbuf[wv] = bv; ((int*)rbuf)[8 + wv] = bi; }
    __syncthreads();
    if (tid == 0){
      float xv = rbuf[0]; int xi = ((int*)rbuf)[8];
      #pragma unroll
      for (int w2 = 1; w2 < 4; ++w2){
        float ov = rbuf[w2]; int oi = ((int*)rbuf)[8 + w2];
        if (ov > xv || (ov == xv && oi < xi)){ xv = ov; xi = oi; }
      }
      sel_v[k] = xv; sel_i[k] = xi; s_s[xi] = -3.0e38f;
    }
    __syncthreads();
  }

  // ---- wave-per-k: c_u, lnc=LN(c_u;g2,b2), S_k/T_k, vk = W3 @ (g1*lnc_k) ----
  {
    int k = wv, e0 = lane, e1 = lane + 64;
    float sig = 1.f / (1.f + __expf(-sel_v[k]));
    long ci = (long)sel_i[k] * DD;
    float c0 = Cmat[ci + e0] * sig, c1 = Cmat[ci + e1] * sig;
    cu_s[k][e0] = c0; cu_s[k][e1] = c1;
    float mean = wave_sum(c0 + c1) * (1.f / DD);
    float d0 = c0 - mean, d1 = c1 - mean;
    float var = wave_sum(d0 * d0 + d1 * d1) * (1.f / DD);
    float rs = rsqrtf(var + EPSL);
    float l0 = d0 * rs * g2[e0] + b2[e0];
    float l1 = d1 * rs * g2[e1] + b2[e1];
    lnc_s[k][e0] = l0; lnc_s[k][e1] = l1;
    float gl0 = g1s[e0] * l0, gl1 = g1s[e1] * l1;
    float S = wave_sum(gl0 + gl1);
    float T = wave_sum(b1s[e0] * l0 + b1s[e1] * l1);
    if (lane == 0){ SkTk[0][k] = S; SkTk[1][k] = T; }
    cw3s[k][e0] = gl0; cw3s[k][e1] = gl1;          // temp: gl vector
    float v0 = 0.f, v1 = 0.f;
    for (int a = 0; a < DD; ++a){
      float gv = cw3s[k][a];
      v0 = fmaf(W3T[a * DD + e0], gv, v0);
      v1 = fmaf(W3T[a * DD + e1], gv, v1);
    }
    vk_s[k][e0] = v0; vk_s[k][e1] = v1;
  }
  __syncthreads();

  // ---- h1[t,k] = rs_t*(x_t.vk_k - mu_t*S_k) + T_k ; softmax over k -> P_kt ----
  for (int step = 0; step < 16; ++step){
    int t = step * 16 + wv * 4 + (lane >> 4);
    int e0 = (lane & 15) * 8;
    const float* xr = item + ((long)b * TT + t) * DD + e0;
    const float* pr = pos + t * DD + e0;
    float4 xa = *(const float4*)xr, xb = *(const float4*)(xr + 4);
    float4 pa = *(const float4*)pr, pb = *(const float4*)(pr + 4);
    float x0 = xa.x + pa.x, x1 = xa.y + pa.y, x2 = xa.z + pa.z, x3 = xa.w + pa.w;
    float x4 = xb.x + pb.x, x5 = xb.y + pb.y, x6 = xb.z + pb.z, x7 = xb.w + pb.w;
    float2 st = *(const float2*)&lnstats[((long)b * TT + t) * 2];
    float h[KK];
    #pragma unroll
    for (int k = 0; k < KK; ++k){
      float4 v0 = *(const float4*)&vk_s[k][e0];
      float4 v1 = *(const float4*)&vk_s[k][e0 + 4];
      float pk = x0 * v0.x + x1 * v0.y + x2 * v0.z + x3 * v0.w
               + x4 * v1.x + x5 * v1.y + x6 * v1.z + x7 * v1.w;
      pk += __shfl_xor(pk, 1); pk += __shfl_xor(pk, 2);
      pk += __shfl_xor(pk, 4); pk += __shfl_xor(pk, 8);
      h[k] = st.y * (pk - st.x * SkTk[0][k]) + SkTk[1][k];
    }
    float p[KK];
    if (m0s[t]){
      p[0] = p[1] = p[2] = p[3] = 0.25f;
    } else {
      float mxh = fmaxf(fmaxf(h[0], h[1]), fmaxf(h[2], h[3]));
      float sme = 0.f;
      #pragma unroll
      for (int k = 0; k < KK; ++k){ p[k] = __expf(h[k] - mxh); sme += p[k]; }
      float inv = 1.f / sme;
      #pragma unroll
      for (int k = 0; k < KK; ++k) p[k] *= inv;
    }
    int kk = lane & 15;
    if (kk < KK) pkt_s[kk][t] = p[kk];
  }
  __syncthreads();

  // ---- P_tk = masked softmax over t of h2log; P = P_kt * P_tk (wave per k) ----
  {
    int k = wv;
    float4 vj = *(const float4*)&h2log[((long)b * KK + k) * TT + lane * 4];
    float v0 = m0s[lane * 4 + 0] ? NEGF : vj.x;
    float v1 = m0s[lane * 4 + 1] ? NEGF : vj.y;
    float v2 = m0s[lane * 4 + 2] ? NEGF : vj.z;
    float v3 = m0s[lane * 4 + 3] ? NEGF : vj.w;
    float mxv = wave_max(fmaxf(fmaxf(v0, v1), fmaxf(v2, v3)));
    float e0 = __expf(v0 - mxv), e1 = __expf(v1 - mxv);
    float e2 = __expf(v2 - mxv), e3 = __expf(v3 - mxv);
    float sm = wave_sum(e0 + e1 + e2 + e3);
    float inv = 1.f / sm;
    float4 pk4 = *(const float4*)&pkt_s[k][lane * 4];
    float4 r;
    r.x = pk4.x * e0 * inv; r.y = pk4.y * e1 * inv;
    r.z = pk4.z * e2 * inv; r.w = pk4.w * e3 * inv;
    *(float4*)&P_s[k][lane * 4] = r;
  }
  __syncthreads();

  // ---- interest_emb raw sums: ie[k] = sum_t x_t * P[k,t] ----
  {
    int q = tid & 31, h = tid >> 5;
    float4 ak[KK];
    #pragma unroll
    for (int k = 0; k < KK; ++k) ak[k] = {0.f, 0.f, 0.f, 0.f};
    for (int t = h; t < TT; t += 8){
      float4 xi = item4[t * 32 + q];
      float4 pp = pos4[t * 32 + q];
      float4 xv; xv.x = xi.x + pp.x; xv.y = xi.y + pp.y; xv.z = xi.z + pp.z; xv.w = xi.w + pp.w;
      #pragma unroll
      for (int k = 0; k < KK; ++k){
        float pv = P_s[k][t];
        ak[k].x = fmaf(pv, xv.x, ak[k].x); ak[k].y = fmaf(pv, xv.y, ak[k].y);
        ak[k].z = fmaf(pv, xv.z, ak[k].z); ak[k].w = fmaf(pv, xv.w, ak[k].w);
      }
    }
    #pragma unroll
    for (int k = 0; k < KK; ++k)
      *(float4*)&arena[h * 512 + k * 128 + q * 4] = ak[k];   // part[8][4][128]
    __syncthreads();
    int e = tid & 127, kh = tid >> 7;
    for (int k2 = kh; k2 < KK; k2 += 2){
      float s = 0.f;
      #pragma unroll
      for (int h2 = 0; h2 < 8; ++h2) s += arena[h2 * 512 + k2 * 128 + e];
      ies_s[k2][e] = s;
    }
  }
  __syncthreads();

  // ---- wave-per-k: LN(ies; g3,b3) in place + cW3[k] = c_u[k] @ W3 ----
  {
    int k = wv, e0 = lane, e1 = lane + 64;
    float v0 = ies_s[k][e0], v1 = ies_s[k][e1];
    float mean = wave_sum(v0 + v1) * (1.f / DD);
    float d0 = v0 - mean, d1 = v1 - mean;
    float var = wave_sum(d0 * d0 + d1 * d1) * (1.f / DD);
    float rs = rsqrtf(var + EPSL);
    ies_s[k][e0] = d0 * rs * g3[e0] + b3[e0];
    ies_s[k][e1] = d1 * rs * g3[e1] + b3[e1];
    float s0 = 0.f, s1 = 0.f;
    for (int e = 0; e < DD; ++e){
      float cv = cu_s[k][e];
      s0 = fmaf(cv, W3[e * DD + e0], s0);
      s1 = fmaf(cv, W3[e * DD + e1], s1);
    }
    cw3s[k][e0] = s0; cw3s[k][e1] = s1;
  }
  if (tid < DD) w4s[tid] = W4[tid];
  __syncthreads();

  // ---- aggregation ----
  float pk0 = pkt_s[0][tid], pk1 = pkt_s[1][tid], pk2 = pkt_s[2][tid], pk3 = pkt_s[3][tid];
  float sv = 0.f;
  for (int a = 0; a < DD; ++a){
    float hp = pk0 * cw3s[0][a] + pk1 * cw3s[1][a] + pk2 * cw3s[2][a] + pk3 * cw3s[3][a];
    sv = fmaf(fast_tanh(hp), w4s[a], sv);
  }
  float h3;
  {
    float v = m0s[tid] ? NEGF : sv;
    float wm = wave_max(v);
    if (lane == 0) rbuf[wv] = wm;
    __syncthreads();
    float mx = fmaxf(fmaxf(rbuf[0], rbuf[1]), fmaxf(rbuf[2], rbuf[3]));
    float ex = __expf(v - mx);
    float ws = wave_sum(ex);
    if (lane == 0) rbuf[4 + wv] = ws;
    __syncthreads();
    float sm = rbuf[4] + rbuf[5] + rbuf[6] + rbuf[7];
    h3 = ex / sm;
  }
  __syncthreads();                         // protect rbuf[0..7] before reuse below
  // wk_k = sum_t P_kt[k][t]*h3[t]
  {
    float w0 = wave_sum(pk0 * h3), w1 = wave_sum(pk1 * h3);
    float w2 = wave_sum(pk2 * h3), w3 = wave_sum(pk3 * h3);
    if (lane == 0){
      rbuf[8 + wv * 4 + 0] = w0; rbuf[8 + wv * 4 + 1] = w1;
      rbuf[8 + wv * 4 + 2] = w2; rbuf[8 + wv * 4 + 3] = w3;
    }
  }
  __syncthreads();
  float wk0 = rbuf[8] + rbuf[12] + rbuf[16] + rbuf[20];
  float wk1 = rbuf[9] + rbuf[13] + rbuf[17] + rbuf[21];
  float wk2 = rbuf[10] + rbuf[14] + rbuf[18] + rbuf[22];
  float wk3 = rbuf[11] + rbuf[15] + rbuf[19] + rbuf[23];
  // c_apt = LN(sum_k wk_k c_u[k]; g4,b4)
  {
    float cp = 0.f;
    if (tid < DD)
      cp = wk0 * cu_s[0][tid] + wk1 * cu_s[1][tid] + wk2 * cu_s[2][tid] + wk3 * cu_s[3][tid];
    float ws = wave_sum((tid < DD) ? cp : 0.f);
    if (lane == 0) rbuf[wv] = ws;
    __syncthreads();
    float mean = (rbuf[0] + rbuf[1] + rbuf[2] + rbuf[3]) * (1.f / DD);
    float d = (tid < DD) ? cp - mean : 0.f;
    float wq = wave_sum(d * d);
    if (lane == 0) rbuf[4 + wv] = wq;
    __syncthreads();
    float var = (rbuf[4] + rbuf[5] + rbuf[6] + rbuf[7]) * (1.f / DD);
    float rs = rsqrtf(var + EPSL);
    if (tid < DD) cas[tid] = d * rs * g4[tid] + b4[tid];
  }
  __syncthreads();
  // e_u = softmax(10*(c_apt . ies_k)); v_u = ies^T e_u
  {
    float c0 = (tid < DD) ? cas[tid] * ies_s[0][tid] : 0.f;
    float c1 = (tid < DD) ? cas[tid] * ies_s[1][tid] : 0.f;
    float c2 = (tid < DD) ? cas[tid] * ies_s[2][tid] : 0.f;
    float c3 = (tid < DD) ? cas[tid] * ies_s[3][tid] : 0.f;
    float w0 = wave_sum(c0), w1 = wave_sum(c1), w2 = wave_sum(c2), w3 = wave_sum(c3);
    if (lane == 0){
      rbuf[8 + wv * 4 + 0] = w0; rbuf[8 + wv * 4 + 1] = w1;
      rbuf[8 + wv * 4 + 2] = w2; rbuf[8 + wv * 4 + 3] = w3;
    }
    __syncthreads();
    float l0 = (rbuf[8] + rbuf[12] + rbuf[16] + rbuf[20]) * 10.f;
    float l1 = (rbuf[9] + rbuf[13] + rbuf[17] + rbuf[21]) * 10.f;
    float l2 = (rbuf[10] + rbuf[14] + rbuf[18] + rbuf[22]) * 10.f;
    float l3 = (rbuf[11] + rbuf[15] + rbuf[19] + rbuf[23]) * 10.f;
    float mx2 = fmaxf(fmaxf(l0, l1), fmaxf(l2, l3));
    float e0 = __expf(l0 - mx2), e1 = __expf(l1 - mx2);
    float e2 = __expf(l2 - mx2), e3 = __expf(l3 - mx2);
    float inv = 1.f / (e0 + e1 + e2 + e3);
    if (tid < DD){
      float r = (ies_s[0][tid] * e0 + ies_s[1][tid] * e1 +
                 ies_s[2][tid] * e2 + ies_s[3][tid] * e3) * inv;
      out[b * DD + tid] = r;
    }
  }
}

// ---------- launch ----------

extern "C" void kernel_launch(void* const* d_in, const int* in_sizes, int n_in,
                              void* d_out, int out_size, void* d_ws, size_t ws_size,
                              hipStream_t stream)
{
  const float* item = (const float*)d_in[0];
  const int*   mask = (const int*)d_in[1];
  const float* W1   = (const float*)d_in[2];
  const float* W2   = (const float*)d_in[3];
  const float* W3   = (const float*)d_in[4];
  const float* W4   = (const float*)d_in[5];
  const float* Wk1  = (const float*)d_in[6];
  const float* Wk2  = (const float*)d_in[7];
  const float* Cm   = (const float*)d_in[8];
  const float* pos  = (const float*)d_in[9];
  const float* g1   = (const float*)d_in[10]; const float* b1 = (const float*)d_in[11];
  const float* g2   = (const float*)d_in[12]; const float* b2 = (const float*)d_in[13];
  const float* g3   = (const float*)d_in[14]; const float* b3 = (const float*)d_in[15];
  const float* g4   = (const float*)d_in[16]; const float* b4 = (const float*)d_in[17];
  float* out = (float*)d_out;

  // workspace: ~7.7 MB
  char* p = (char*)d_ws;
  float* att     = (float*)(p);                  // B*T f32       = 1048576 B
  float* h2log   = (float*)(p + 1048576);        // B*K*T f32     = 4194304 B
  float* lnstats = (float*)(p + 5242880);        // B*T*2 f32     = 2097152 B
  float* W3T     = (float*)(p + 7340032);        // 128*128 f32   = 65536 B
  float* CT      = (float*)(p + 7405568);        // 128*500 f32   = 256000 B
  // packed weights in d_out (393216 B < 524288 B); consumed only by k_big6m,
  // fully overwritten by k_fused's out-write at the end of every launch.
  uint4* whi = (uint4*)d_out;                    // 196608 B
  uint4* wlo = whi + 12288;                      // 196608 B
  (void)in_sizes; (void)n_in; (void)out_size; (void)ws_size;

  k_preppack <<<dim3(362), dim3(256), 0, stream>>>(W1, W3, Wk1, Cm, whi, wlo, W3T, CT);
  k_big6m    <<<dim3((BB * TT) / 128), dim3(512), 0, stream>>>(item, pos, whi, wlo, W2, Wk2,
                                                               att, h2log, lnstats);
  k_fused    <<<dim3(BB), dim3(256), 0, stream>>>(item, pos, mask, att, h2log, lnstats,
                                                  Cm, CT, W3, W3T,
                                                  g1, b1, g2, b2, g3, b3, g4, b4, W4, out);
}

// Round 13
// 281.735 us; speedup vs baseline: 1.1993x; 1.1993x over previous
//
#include <hip/hip_runtime.h>
#include <hip/hip_bf16.h>
#include <string.h>

#define BB 1024
#define TT 256
#define DD 128
#define KK 4
#define CC 500
#define NEGF (-4294967296.0f)   // float(-2**32+1) rounds to -2^32
#define EPSL 1e-3f

typedef __attribute__((ext_vector_type(8))) short bf16x8;
typedef __attribute__((ext_vector_type(4))) float f32x4;

// ---------- helpers ----------

__device__ __forceinline__ float fast_tanh(float x){
  float ax = fabsf(x);
  float e  = __expf(2.0f * ax);
  float t  = 1.0f - 2.0f * __builtin_amdgcn_rcpf(e + 1.0f);  // e=inf -> rcp=0 -> t=1
  return copysignf(t, x);
}

__device__ __forceinline__ unsigned short bfbits(float f){
  __hip_bfloat16 h = __float2bfloat16(f);
  unsigned short u;
  memcpy(&u, &h, 2);
  return u;
}
__device__ __forceinline__ float bf2f(unsigned short u){
  return __uint_as_float(((unsigned)u) << 16);
}

__device__ __forceinline__ float wave_sum(float v){
  #pragma unroll
  for (int o = 32; o > 0; o >>= 1) v += __shfl_xor(v, o);
  return v;
}
__device__ __forceinline__ float wave_max(float v){
  #pragma unroll
  for (int o = 32; o > 0; o >>= 1) v = fmaxf(v, __shfl_xor(v, o));
  return v;
}

// ---------- K0: pack weights to MFMA B-frag order (hi/lo) + W3T/CT transposes ----------

__global__ __launch_bounds__(256) void k_preppack(
    const float* __restrict__ W1, const float* __restrict__ W3,
    const float* __restrict__ Wk1, const float* __restrict__ Cmat,
    uint4* __restrict__ whi, uint4* __restrict__ wlo,
    float* __restrict__ W3T, float* __restrict__ CT)
{
  int gid = blockIdx.x * 256 + threadIdx.x;
  if (gid < 12288){
    int lane = gid & 63;
    int frag = gid >> 6;
    int n = frag & 7, kt = (frag >> 3) & 3, w = frag >> 5;
    const float* Wp = (w == 0) ? W1 : (w == 1) ? W3 : (Wk1 + (long)(w - 2) * DD * DD);
    int col = n * 16 + (lane & 15);
    int k0 = kt * 32 + (lane >> 4) * 8;
    unsigned int H[4], L[4];
    #pragma unroll
    for (int d = 0; d < 4; ++d){
      float v0 = Wp[(long)(k0 + 2 * d) * DD + col];
      float v1 = Wp[(long)(k0 + 2 * d + 1) * DD + col];
      unsigned short h0 = bfbits(v0); unsigned short l0 = bfbits(v0 - bf2f(h0));
      unsigned short h1 = bfbits(v1); unsigned short l1 = bfbits(v1 - bf2f(h1));
      H[d] = (unsigned)h0 | ((unsigned)h1 << 16);
      L[d] = (unsigned)l0 | ((unsigned)l1 << 16);
    }
    whi[gid] = make_uint4(H[0], H[1], H[2], H[3]);
    wlo[gid] = make_uint4(L[0], L[1], L[2], L[3]);
  } else {
    int j = gid - 12288;
    if (j < DD * DD){
      int a = j >> 7, e = j & 127;
      W3T[j] = W3[e * DD + a];
    } else {
      j -= DD * DD;
      if (j < DD * CC){
        int e = j / CC, c = j - e * CC;
        CT[j] = Cmat[c * DD + e];
      }
    }
  }
}

// ---------- K1: MFMA fused 6x GEMM, split-bf16; 8 waves (4-M x 2-N), 128 rows ----------
// Round-6 measured-best structure: barrier-minimal (1 sync after staging, 1 before
// combined epilogue), per-pass dedicated LDS scratch, setprio around MFMA cluster.

__global__ __launch_bounds__(512, 4) void k_big6m(
    const float* __restrict__ item, const float* __restrict__ pos,
    const uint4* __restrict__ whi, const uint4* __restrict__ wlo,
    const float* __restrict__ W2, const float* __restrict__ Wk2,
    float* __restrict__ att, float* __restrict__ h2log, float* __restrict__ lnstats)
{
  __shared__ uint4 smem4[4096];                 // 64 KiB: Ahi [128]x256B, Alo at +32KB
  __shared__ float dscr[5][128][2];             // 5 KB  per-pass dot partials (N-halves)
  __shared__ float sscr[2][128][2];             // 2 KB  W3 LN-stat partials (s, q)
  char* smem = (char*)smem4;
  const int tid = threadIdx.x, lane = tid & 63, wv = tid >> 6;
  const int ni = wv & 1, mi = wv >> 1;          // N-half, M-quarter
  const long rbase = (long)blockIdx.x * 128;
  const int r15 = lane & 15, g = lane >> 4;
  const f32x4 ZV = {0.f, 0.f, 0.f, 0.f};

  // ---- stage A = item+pos as hi/lo bf16, rows of 256B, XOR-swizzled ----
  #pragma unroll
  for (int it = 0; it < 4; ++it){
    int cid = tid + it * 512;                   // 2048 chunks of 8 elems
    int row = cid >> 4, c0 = (cid & 15) * 8;
    const float* src = item + (rbase + row) * DD + c0;
    const float* ps  = pos + (int)((rbase + row) & 255) * DD + c0;
    float4 f0 = *(const float4*)src;
    float4 f1 = *(const float4*)(src + 4);
    float4 p0 = *(const float4*)ps;
    float4 p1 = *(const float4*)(ps + 4);
    float v[8] = {f0.x + p0.x, f0.y + p0.y, f0.z + p0.z, f0.w + p0.w,
                  f1.x + p1.x, f1.y + p1.y, f1.z + p1.z, f1.w + p1.w};
    unsigned int H[4], L[4];
    #pragma unroll
    for (int d = 0; d < 4; ++d){
      unsigned short h0 = bfbits(v[2 * d]);     unsigned short l0 = bfbits(v[2 * d]     - bf2f(h0));
      unsigned short h1 = bfbits(v[2 * d + 1]); unsigned short l1 = bfbits(v[2 * d + 1] - bf2f(h1));
      H[d] = (unsigned)h0 | ((unsigned)h1 << 16);
      L[d] = (unsigned)l0 | ((unsigned)l1 << 16);
    }
    int byt = (c0 * 2) ^ ((row & 7) << 4);
    *(uint4*)(smem + row * 256 + byt)         = make_uint4(H[0], H[1], H[2], H[3]);
    *(uint4*)(smem + 32768 + row * 256 + byt) = make_uint4(L[0], L[1], L[2], L[3]);
  }
  __syncthreads();

  const int wrow = mi * 32;

  // ---- 5 dot-weights: W1 (->att) and W_k1[0..3] (->h2log); no barriers ----
  const int WL[5] = {0, 2, 3, 4, 5};
  #pragma unroll
  for (int wi = 0; wi < 5; ++wi){
    const int w = WL[wi];
    f32x4 acc[2][4];
    #pragma unroll
    for (int m = 0; m < 2; ++m)
      #pragma unroll
      for (int n = 0; n < 4; ++n) acc[m][n] = ZV;

    __builtin_amdgcn_s_setprio(1);
    #pragma unroll
    for (int kt = 0; kt < 4; ++kt){
      bf16x8 ah[2], al[2];
      #pragma unroll
      for (int m = 0; m < 2; ++m){
        int row = wrow + m * 16 + r15;
        int byt = (kt * 64 + g * 16) ^ ((row & 7) << 4);
        ah[m] = *(const bf16x8*)(smem + row * 256 + byt);
        al[m] = *(const bf16x8*)(smem + 32768 + row * 256 + byt);
      }
      const uint4* bhp = whi + (long)((w * 4 + kt) * 8 + ni * 4) * 64 + lane;
      const uint4* blp = wlo + (long)((w * 4 + kt) * 8 + ni * 4) * 64 + lane;
      #pragma unroll
      for (int n = 0; n < 4; ++n){
        uint4 bhu = bhp[n * 64], blu = blp[n * 64];
        bf16x8 bh = *(const bf16x8*)&bhu;
        bf16x8 bl = *(const bf16x8*)&blu;
        #pragma unroll
        for (int m = 0; m < 2; ++m){
          acc[m][n] = __builtin_amdgcn_mfma_f32_16x16x32_bf16(ah[m], bh, acc[m][n], 0, 0, 0);
          acc[m][n] = __builtin_amdgcn_mfma_f32_16x16x32_bf16(ah[m], bl, acc[m][n], 0, 0, 0);
          acc[m][n] = __builtin_amdgcn_mfma_f32_16x16x32_bf16(al[m], bh, acc[m][n], 0, 0, 0);
        }
      }
    }
    __builtin_amdgcn_s_setprio(0);

    // epilogue: partial dot over this wave's 64 cols -> dedicated scratch slot
    const float* vp = (w == 0) ? W2 : (Wk2 + (w - 2) * DD);
    float pd[2][4] = {{0, 0, 0, 0}, {0, 0, 0, 0}};
    #pragma unroll
    for (int n = 0; n < 4; ++n){
      float vv = vp[ni * 64 + n * 16 + r15];
      #pragma unroll
      for (int m = 0; m < 2; ++m)
        #pragma unroll
        for (int j = 0; j < 4; ++j)
          pd[m][j] = fmaf(fast_tanh(acc[m][n][j]), vv, pd[m][j]);
    }
    #pragma unroll
    for (int m = 0; m < 2; ++m)
      #pragma unroll
      for (int j = 0; j < 4; ++j){
        float v = pd[m][j];
        v += __shfl_xor(v, 1); v += __shfl_xor(v, 2);
        v += __shfl_xor(v, 4); v += __shfl_xor(v, 8);
        if (r15 == 0) dscr[wi][wrow + m * 16 + g * 4 + j][ni] = v;
      }
  }

  // ---- W3 pass: per-row LN stat partials {s, q} of y = x@W3 ----
  {
    f32x4 acc[2][4];
    #pragma unroll
    for (int m = 0; m < 2; ++m)
      #pragma unroll
      for (int n = 0; n < 4; ++n) acc[m][n] = ZV;

    __builtin_amdgcn_s_setprio(1);
    #pragma unroll
    for (int kt = 0; kt < 4; ++kt){
      bf16x8 ah[2], al[2];
      #pragma unroll
      for (int m = 0; m < 2; ++m){
        int row = wrow + m * 16 + r15;
        int byt = (kt * 64 + g * 16) ^ ((row & 7) << 4);
        ah[m] = *(const bf16x8*)(smem + row * 256 + byt);
        al[m] = *(const bf16x8*)(smem + 32768 + row * 256 + byt);
      }
      const uint4* bhp = whi + (long)((1 * 4 + kt) * 8 + ni * 4) * 64 + lane;
      const uint4* blp = wlo + (long)((1 * 4 + kt) * 8 + ni * 4) * 64 + lane;
      #pragma unroll
      for (int n = 0; n < 4; ++n){
        uint4 bhu = bhp[n * 64], blu = blp[n * 64];
        bf16x8 bh = *(const bf16x8*)&bhu;
        bf16x8 bl = *(const bf16x8*)&blu;
        #pragma unroll
        for (int m = 0; m < 2; ++m){
          acc[m][n] = __builtin_amdgcn_mfma_f32_16x16x32_bf16(ah[m], bh, acc[m][n], 0, 0, 0);
          acc[m][n] = __builtin_amdgcn_mfma_f32_16x16x32_bf16(ah[m], bl, acc[m][n], 0, 0, 0);
          acc[m][n] = __builtin_amdgcn_mfma_f32_16x16x32_bf16(al[m], bh, acc[m][n], 0, 0, 0);
        }
      }
    }
    __builtin_amdgcn_s_setprio(0);

    #pragma unroll
    for (int m = 0; m < 2; ++m)
      #pragma unroll
      for (int j = 0; j < 4; ++j){
        float s = 0.f, q = 0.f;
        #pragma unroll
        for (int n = 0; n < 4; ++n){
          float y = acc[m][n][j];
          s += y; q = fmaf(y, y, q);
        }
        s += __shfl_xor(s, 1); s += __shfl_xor(s, 2);
        s += __shfl_xor(s, 4); s += __shfl_xor(s, 8);
        q += __shfl_xor(q, 1); q += __shfl_xor(q, 2);
        q += __shfl_xor(q, 4); q += __shfl_xor(q, 8);
        if (r15 == 0){
          int row = wrow + m * 16 + g * 4 + j;
          sscr[0][row][ni] = s;
          sscr[1][row][ni] = q;
        }
      }
  }
  __syncthreads();

  // ---- single combined epilogue: merge N-halves, write att/h2log/lnstats ----
  if (tid < 128){
    long rg = rbase + tid;
    long b = rg >> 8; int t = (int)(rg & 255);
    att[rg] = dscr[0][tid][0] + dscr[0][tid][1];
    #pragma unroll
    for (int wi = 1; wi < 5; ++wi)
      h2log[(b * KK + (wi - 1)) * TT + t] = dscr[wi][tid][0] + dscr[wi][tid][1];
    float s = sscr[0][tid][0] + sscr[0][tid][1];
    float q = sscr[1][tid][0] + sscr[1][tid][1];
    float mu = s * (1.f / DD);
    float var = q * (1.f / DD) - mu * mu;
    float rs = rsqrtf(var + EPSL);
    float2 st; st.x = mu; st.y = rs;
    *(float2*)&lnstats[rg * 2] = st;
  }
}

// ---------- K2: fused per-batch pipeline, occupancy-first (~39 KB LDS) ----------

__global__ __launch_bounds__(256, 4) void k_fused(
    const float* __restrict__ item, const float* __restrict__ pos,
    const int* __restrict__ mask, const float* __restrict__ att,
    const float* __restrict__ h2log, const float* __restrict__ lnstats,
    const float* __restrict__ Cmat, const float* __restrict__ CT,
    const float* __restrict__ W3, const float* __restrict__ W3T,
    const float* __restrict__ g1, const float* __restrict__ b1,
    const float* __restrict__ g2, const float* __restrict__ b2,
    const float* __restrict__ g3, const float* __restrict__ b3,
    const float* __restrict__ g4, const float* __restrict__ b4,
    const float* __restrict__ W4, float* __restrict__ out)
{
  __shared__ float arena[4096];         // 16 KB phase-shared
  __shared__ float pkt_s[KK][TT];       // 4 KB
  __shared__ float P_s[KK][TT];         // 4 KB
  __shared__ float lnc_s[KK][DD];       // 2 KB
  __shared__ float cu_s[KK][DD];        // 2 KB
  __shared__ float vk_s[KK][DD];        // 2 KB
  __shared__ float cw3s[KK][DD];        // 2 KB (gl-temp, cW3 later)
  __shared__ float ies_s[KK][DD];       // 2 KB
  __shared__ float a_s[TT];             // 1 KB
  __shared__ int   m0s[TT];             // 1 KB
  __shared__ float g1s[DD], b1s[DD];    // 1 KB
  __shared__ float cas[DD], w4s[DD];    // 1 KB
  __shared__ float rbuf[32];
  __shared__ float sel_v[KK];
  __shared__ int   sel_i[KK];
  __shared__ float SkTk[2][KK];

  const int tid = threadIdx.x;
  const long b = blockIdx.x;
  const int lane = tid & 63, wv = tid >> 6;

  float attv = att[b * TT + tid];
  int   mk   = mask[b * TT + tid];
  if (tid < DD){ g1s[tid] = g1[tid]; b1s[tid] = b1[tid]; }
  m0s[tid] = (mk == 0);

  // ---- att softmax -> a_s ----
  {
    float v = (mk == 0) ? NEGF : attv;
    float wm = wave_max(v);
    if (lane == 0) rbuf[wv] = wm;
    __syncthreads();
    float mx = fmaxf(fmaxf(rbuf[0], rbuf[1]), fmaxf(rbuf[2], rbuf[3]));
    float ex = __expf(v - mx);
    float ws = wave_sum(ex);
    if (lane == 0) rbuf[4 + wv] = ws;
    __syncthreads();
    float sm = rbuf[4] + rbuf[5] + rbuf[6] + rbuf[7];
    a_s[tid] = ex / sm;
  }
  __syncthreads();

  const float4* item4 = (const float4*)(item + (long)b * TT * DD);
  const float4* pos4  = (const float4*)pos;

  // ---- z_u = x^T a ----
  {
    int q = tid & 31, h = tid >> 5;
    float4 acc = {0.f, 0.f, 0.f, 0.f};
    for (int t = h; t < TT; t += 8){
      float4 xi = item4[t * 32 + q];
      float4 pp = pos4[t * 32 + q];
      float av = a_s[t];
      acc.x = fmaf(av, xi.x + pp.x, acc.x);
      acc.y = fmaf(av, xi.y + pp.y, acc.y);
      acc.z = fmaf(av, xi.z + pp.z, acc.z);
      acc.w = fmaf(av, xi.w + pp.w, acc.w);
    }
    *(float4*)&arena[h * 128 + q * 4] = acc;      // zpart[8][128]
    __syncthreads();
    if (tid < DD){
      float z = 0.f;
      #pragma unroll
      for (int h2 = 0; h2 < 8; ++h2) z += arena[h2 * 128 + tid];
      arena[1024 + tid] = z;                      // zs
    }
    __syncthreads();
  }
  float* zs  = arena + 1024;                      // [128]
  float* s_s = arena + 1152;                      // [512]

  // ---- s_u = z_u @ C^T ----
  for (int c = tid; c < 512; c += 256){
    float s = -3.0e38f;
    if (c < CC){
      s = 0.f;
      for (int e = 0; e < DD; ++e) s = fmaf(zs[e], CT[e * CC + c], s);
    }
    s_s[c] = s;
  }
  __syncthreads();

  // ---- top-4 (descending, ties -> lowest index) ----
  for (int k = 0; k < KK; ++k){
    float bv = -3.0e38f; int bi = 1 << 20;
    for (int c = tid; c < 512; c += 256){
      float sv = s_s[c];
      if (sv > bv || (sv == bv && c < bi)){ bv = sv; bi = c; }
    }
    #pragma unroll
    for (int o = 32; o > 0; o >>= 1){
      float ov = __shfl_xor(bv, o); int oi = __shfl_xor(bi, o);
      if (ov > bv || (ov == bv && oi < bi)){ bv = ov; bi = oi; }
    }
    if (lane == 0){ rbuf[wv] = bv; ((int*)rbuf)[8 + wv] = bi; }
    __syncthreads();
    if (tid == 0){
      float xv = rbuf[0]; int xi = ((int*)rbuf)[8];
      #pragma unroll
      for (int w2 = 1; w2 < 4; ++w2){
        float ov = rbuf[w2]; int oi = ((int*)rbuf)[8 + w2];
        if (ov > xv || (ov == xv && oi < xi)){ xv = ov; xi = oi; }
      }
      sel_v[k] = xv; sel_i[k] = xi; s_s[xi] = -3.0e38f;
    }
    __syncthreads();
  }

  // ---- wave-per-k: c_u, lnc=LN(c_u;g2,b2), S_k/T_k, vk = W3 @ (g1*lnc_k) ----
  {
    int k = wv, e0 = lane, e1 = lane + 64;
    float sig = 1.f / (1.f + __expf(-sel_v[k]));
    long ci = (long)sel_i[k] * DD;
    float c0 = Cmat[ci + e0] * sig, c1 = Cmat[ci + e1] * sig;
    cu_s[k][e0] = c0; cu_s[k][e1] = c1;
    float mean = wave_sum(c0 + c1) * (1.f / DD);
    float d0 = c0 - mean, d1 = c1 - mean;
    float var = wave_sum(d0 * d0 + d1 * d1) * (1.f / DD);
    float rs = rsqrtf(var + EPSL);
    float l0 = d0 * rs * g2[e0] + b2[e0];
    float l1 = d1 * rs * g2[e1] + b2[e1];
    lnc_s[k][e0] = l0; lnc_s[k][e1] = l1;
    float gl0 = g1s[e0] * l0, gl1 = g1s[e1] * l1;
    float S = wave_sum(gl0 + gl1);
    float T = wave_sum(b1s[e0] * l0 + b1s[e1] * l1);
    if (lane == 0){ SkTk[0][k] = S; SkTk[1][k] = T; }
    cw3s[k][e0] = gl0; cw3s[k][e1] = gl1;          // temp: gl vector
    float v0 = 0.f, v1 = 0.f;
    for (int a = 0; a < DD; ++a){
      float gv = cw3s[k][a];
      v0 = fmaf(W3T[a * DD + e0], gv, v0);
      v1 = fmaf(W3T[a * DD + e1], gv, v1);
    }
    vk_s[k][e0] = v0; vk_s[k][e1] = v1;
  }
  __syncthreads();

  // ---- h1[t,k] = rs_t*(x_t.vk_k - mu_t*S_k) + T_k ; softmax over k -> P_kt ----
  for (int step = 0; step < 16; ++step){
    int t = step * 16 + wv * 4 + (lane >> 4);
    int e0 = (lane & 15) * 8;
    const float* xr = item + ((long)b * TT + t) * DD + e0;
    const float* pr = pos + t * DD + e0;
    float4 xa = *(const float4*)xr, xb = *(const float4*)(xr + 4);
    float4 pa = *(const float4*)pr, pb = *(const float4*)(pr + 4);
    float x0 = xa.x + pa.x, x1 = xa.y + pa.y, x2 = xa.z + pa.z, x3 = xa.w + pa.w;
    float x4 = xb.x + pb.x, x5 = xb.y + pb.y, x6 = xb.z + pb.z, x7 = xb.w + pb.w;
    float2 st = *(const float2*)&lnstats[((long)b * TT + t) * 2];
    float h[KK];
    #pragma unroll
    for (int k = 0; k < KK; ++k){
      float4 v0 = *(const float4*)&vk_s[k][e0];
      float4 v1 = *(const float4*)&vk_s[k][e0 + 4];
      float pk = x0 * v0.x + x1 * v0.y + x2 * v0.z + x3 * v0.w
               + x4 * v1.x + x5 * v1.y + x6 * v1.z + x7 * v1.w;
      pk += __shfl_xor(pk, 1); pk += __shfl_xor(pk, 2);
      pk += __shfl_xor(pk, 4); pk += __shfl_xor(pk, 8);
      h[k] = st.y * (pk - st.x * SkTk[0][k]) + SkTk[1][k];
    }
    float p[KK];
    if (m0s[t]){
      p[0] = p[1] = p[2] = p[3] = 0.25f;
    } else {
      float mxh = fmaxf(fmaxf(h[0], h[1]), fmaxf(h[2], h[3]));
      float sme = 0.f;
      #pragma unroll
      for (int k = 0; k < KK; ++k){ p[k] = __expf(h[k] - mxh); sme += p[k]; }
      float inv = 1.f / sme;
      #pragma unroll
      for (int k = 0; k < KK; ++k) p[k] *= inv;
    }
    int kk = lane & 15;
    if (kk < KK) pkt_s[kk][t] = p[kk];
  }
  __syncthreads();

  // ---- P_tk = masked softmax over t of h2log; P = P_kt * P_tk (wave per k) ----
  {
    int k = wv;
    float4 vj = *(const float4*)&h2log[((long)b * KK + k) * TT + lane * 4];
    float v0 = m0s[lane * 4 + 0] ? NEGF : vj.x;
    float v1 = m0s[lane * 4 + 1] ? NEGF : vj.y;
    float v2 = m0s[lane * 4 + 2] ? NEGF : vj.z;
    float v3 = m0s[lane * 4 + 3] ? NEGF : vj.w;
    float mxv = wave_max(fmaxf(fmaxf(v0, v1), fmaxf(v2, v3)));
    float e0 = __expf(v0 - mxv), e1 = __expf(v1 - mxv);
    float e2 = __expf(v2 - mxv), e3 = __expf(v3 - mxv);
    float sm = wave_sum(e0 + e1 + e2 + e3);
    float inv = 1.f / sm;
    float4 pk4 = *(const float4*)&pkt_s[k][lane * 4];
    float4 r;
    r.x = pk4.x * e0 * inv; r.y = pk4.y * e1 * inv;
    r.z = pk4.z * e2 * inv; r.w = pk4.w * e3 * inv;
    *(float4*)&P_s[k][lane * 4] = r;
  }
  __syncthreads();

  // ---- interest_emb raw sums: ie[k] = sum_t x_t * P[k,t] ----
  {
    int q = tid & 31, h = tid >> 5;
    float4 ak[KK];
    #pragma unroll
    for (int k = 0; k < KK; ++k) ak[k] = {0.f, 0.f, 0.f, 0.f};
    for (int t = h; t < TT; t += 8){
      float4 xi = item4[t * 32 + q];
      float4 pp = pos4[t * 32 + q];
      float4 xv; xv.x = xi.x + pp.x; xv.y = xi.y + pp.y; xv.z = xi.z + pp.z; xv.w = xi.w + pp.w;
      #pragma unroll
      for (int k = 0; k < KK; ++k){
        float pv = P_s[k][t];
        ak[k].x = fmaf(pv, xv.x, ak[k].x); ak[k].y = fmaf(pv, xv.y, ak[k].y);
        ak[k].z = fmaf(pv, xv.z, ak[k].z); ak[k].w = fmaf(pv, xv.w, ak[k].w);
      }
    }
    #pragma unroll
    for (int k = 0; k < KK; ++k)
      *(float4*)&arena[h * 512 + k * 128 + q * 4] = ak[k];   // part[8][4][128]
    __syncthreads();
    int e = tid & 127, kh = tid >> 7;
    for (int k2 = kh; k2 < KK; k2 += 2){
      float s = 0.f;
      #pragma unroll
      for (int h2 = 0; h2 < 8; ++h2) s += arena[h2 * 512 + k2 * 128 + e];
      ies_s[k2][e] = s;
    }
  }
  __syncthreads();

  // ---- wave-per-k: LN(ies; g3,b3) in place + cW3[k] = c_u[k] @ W3 ----
  {
    int k = wv, e0 = lane, e1 = lane + 64;
    float v0 = ies_s[k][e0], v1 = ies_s[k][e1];
    float mean = wave_sum(v0 + v1) * (1.f / DD);
    float d0 = v0 - mean, d1 = v1 - mean;
    float var = wave_sum(d0 * d0 + d1 * d1) * (1.f / DD);
    float rs = rsqrtf(var + EPSL);
    ies_s[k][e0] = d0 * rs * g3[e0] + b3[e0];
    ies_s[k][e1] = d1 * rs * g3[e1] + b3[e1];
    float s0 = 0.f, s1 = 0.f;
    for (int e = 0; e < DD; ++e){
      float cv = cu_s[k][e];
      s0 = fmaf(cv, W3[e * DD + e0], s0);
      s1 = fmaf(cv, W3[e * DD + e1], s1);
    }
    cw3s[k][e0] = s0; cw3s[k][e1] = s1;
  }
  if (tid < DD) w4s[tid] = W4[tid];
  __syncthreads();

  // ---- aggregation ----
  float pk0 = pkt_s[0][tid], pk1 = pkt_s[1][tid], pk2 = pkt_s[2][tid], pk3 = pkt_s[3][tid];
  float sv = 0.f;
  for (int a = 0; a < DD; ++a){
    float hp = pk0 * cw3s[0][a] + pk1 * cw3s[1][a] + pk2 * cw3s[2][a] + pk3 * cw3s[3][a];
    sv = fmaf(fast_tanh(hp), w4s[a], sv);
  }
  float h3;
  {
    float v = m0s[tid] ? NEGF : sv;
    float wm = wave_max(v);
    if (lane == 0) rbuf[wv] = wm;
    __syncthreads();
    float mx = fmaxf(fmaxf(rbuf[0], rbuf[1]), fmaxf(rbuf[2], rbuf[3]));
    float ex = __expf(v - mx);
    float ws = wave_sum(ex);
    if (lane == 0) rbuf[4 + wv] = ws;
    __syncthreads();
    float sm = rbuf[4] + rbuf[5] + rbuf[6] + rbuf[7];
    h3 = ex / sm;
  }
  __syncthreads();                         // protect rbuf[0..7] before reuse below
  // wk_k = sum_t P_kt[k][t]*h3[t]
  {
    float w0 = wave_sum(pk0 * h3), w1 = wave_sum(pk1 * h3);
    float w2 = wave_sum(pk2 * h3), w3 = wave_sum(pk3 * h3);
    if (lane == 0){
      rbuf[8 + wv * 4 + 0] = w0; rbuf[8 + wv * 4 + 1] = w1;
      rbuf[8 + wv * 4 + 2] = w2; rbuf[8 + wv * 4 + 3] = w3;
    }
  }
  __syncthreads();
  float wk0 = rbuf[8] + rbuf[12] + rbuf[16] + rbuf[20];
  float wk1 = rbuf[9] + rbuf[13] + rbuf[17] + rbuf[21];
  float wk2 = rbuf[10] + rbuf[14] + rbuf[18] + rbuf[22];
  float wk3 = rbuf[11] + rbuf[15] + rbuf[19] + rbuf[23];
  // c_apt = LN(sum_k wk_k c_u[k]; g4,b4)
  {
    float cp = 0.f;
    if (tid < DD)
      cp = wk0 * cu_s[0][tid] + wk1 * cu_s[1][tid] + wk2 * cu_s[2][tid] + wk3 * cu_s[3][tid];
    float ws = wave_sum((tid < DD) ? cp : 0.f);
    if (lane == 0) rbuf[wv] = ws;
    __syncthreads();
    float mean = (rbuf[0] + rbuf[1] + rbuf[2] + rbuf[3]) * (1.f / DD);
    float d = (tid < DD) ? cp - mean : 0.f;
    float wq = wave_sum(d * d);
    if (lane == 0) rbuf[4 + wv] = wq;
    __syncthreads();
    float var = (rbuf[4] + rbuf[5] + rbuf[6] + rbuf[7]) * (1.f / DD);
    float rs = rsqrtf(var + EPSL);
    if (tid < DD) cas[tid] = d * rs * g4[tid] + b4[tid];
  }
  __syncthreads();
  // e_u = softmax(10*(c_apt . ies_k)); v_u = ies^T e_u
  {
    float c0 = (tid < DD) ? cas[tid] * ies_s[0][tid] : 0.f;
    float c1 = (tid < DD) ? cas[tid] * ies_s[1][tid] : 0.f;
    float c2 = (tid < DD) ? cas[tid] * ies_s[2][tid] : 0.f;
    float c3 = (tid < DD) ? cas[tid] * ies_s[3][tid] : 0.f;
    float w0 = wave_sum(c0), w1 = wave_sum(c1), w2 = wave_sum(c2), w3 = wave_sum(c3);
    if (lane == 0){
      rbuf[8 + wv * 4 + 0] = w0; rbuf[8 + wv * 4 + 1] = w1;
      rbuf[8 + wv * 4 + 2] = w2; rbuf[8 + wv * 4 + 3] = w3;
    }
    __syncthreads();
    float l0 = (rbuf[8] + rbuf[12] + rbuf[16] + rbuf[20]) * 10.f;
    float l1 = (rbuf[9] + rbuf[13] + rbuf[17] + rbuf[21]) * 10.f;
    float l2 = (rbuf[10] + rbuf[14] + rbuf[18] + rbuf[22]) * 10.f;
    float l3 = (rbuf[11] + rbuf[15] + rbuf[19] + rbuf[23]) * 10.f;
    float mx2 = fmaxf(fmaxf(l0, l1), fmaxf(l2, l3));
    float e0 = __expf(l0 - mx2), e1 = __expf(l1 - mx2);
    float e2 = __expf(l2 - mx2), e3 = __expf(l3 - mx2);
    float inv = 1.f / (e0 + e1 + e2 + e3);
    if (tid < DD){
      float r = (ies_s[0][tid] * e0 + ies_s[1][tid] * e1 +
                 ies_s[2][tid] * e2 + ies_s[3][tid] * e3) * inv;
      out[b * DD + tid] = r;
    }
  }
}

// ---------- launch ----------

extern "C" void kernel_launch(void* const* d_in, const int* in_sizes, int n_in,
                              void* d_out, int out_size, void* d_ws, size_t ws_size,
                              hipStream_t stream)
{
  const float* item = (const float*)d_in[0];
  const int*   mask = (const int*)d_in[1];
  const float* W1   = (const float*)d_in[2];
  const float* W2   = (const float*)d_in[3];
  const float* W3   = (const float*)d_in[4];
  const float* W4   = (const float*)d_in[5];
  const float* Wk1  = (const float*)d_in[6];
  const float* Wk2  = (const float*)d_in[7];
  const float* Cm   = (const float*)d_in[8];
  const float* pos  = (const float*)d_in[9];
  const float* g1   = (const float*)d_in[10]; const float* b1 = (const float*)d_in[11];
  const float* g2   = (const float*)d_in[12]; const float* b2 = (const float*)d_in[13];
  const float* g3   = (const float*)d_in[14]; const float* b3 = (const float*)d_in[15];
  const float* g4   = (const float*)d_in[16]; const float* b4 = (const float*)d_in[17];
  float* out = (float*)d_out;

  // workspace: ~7.7 MB
  char* p = (char*)d_ws;
  float* att     = (float*)(p);                  // B*T f32       = 1048576 B
  float* h2log   = (float*)(p + 1048576);        // B*K*T f32     = 4194304 B
  float* lnstats = (float*)(p + 5242880);        // B*T*2 f32     = 2097152 B
  float* W3T     = (float*)(p + 7340032);        // 128*128 f32   = 65536 B
  float* CT      = (float*)(p + 7405568);        // 128*500 f32   = 256000 B
  // packed weights in d_out (393216 B < 524288 B); consumed only by k_big6m,
  // fully overwritten by k_fused's out-write at the end of every launch.
  uint4* whi = (uint4*)d_out;                    // 196608 B
  uint4* wlo = whi + 12288;                      // 196608 B
  (void)in_sizes; (void)n_in; (void)out_size; (void)ws_size;

  k_preppack <<<dim3(362), dim3(256), 0, stream>>>(W1, W3, Wk1, Cm, whi, wlo, W3T, CT);
  k_big6m    <<<dim3((BB * TT) / 128), dim3(512), 0, stream>>>(item, pos, whi, wlo, W2, Wk2,
                                                               att, h2log, lnstats);
  k_fused    <<<dim3(BB), dim3(256), 0, stream>>>(item, pos, mask, att, h2log, lnstats,
                                                  Cm, CT, W3, W3T,
                                                  g1, b1, g2, b2, g3, b3, g4, b4, W4, out);
}